// Round 14
// baseline (1070.910 us; speedup 1.0000x reference)
//
#include <hip/hip_runtime.h>

#define BATCH 256
#define L 1024
#define C 16
#define NLEV 10
#define POOL 512          // pooled cols per level per channel
#define PCOLS 5632        // 11*512
#define FDIM 90112        // C*PCOLS
#define H1 128
#define H2 64

#define KB 32
#define MTILE 128
#define LDA 36
#define ATILE (MTILE * LDA)           // floats per A buffer
#define FC1_LDS_BYTES (2 * 2 * ATILE * 4)   // 2 bufs x (A + W) = 73728 B

#define BUFSZ 16896       // 16384 + 16384/32 skew pad
#define TREE_LDS_BYTES ((2*BUFSZ + 32) * 4)

typedef float f32x4 __attribute__((ext_vector_type(4)));

__device__ __forceinline__ int skew(int i) { return i + (i >> 5); }

// ---------------- Kernel 1: leaf + hierarchical conv tree + pooling ----------------
// (unchanged from R13: 512 thr, 2 pos/thread, skewed dbuf LDS, scalar weights,
//  direct coalesced pooled stores, ONE barrier per level; ~90 us)
__launch_bounds__(512, 2)
__global__ void tree_kernel(const float* __restrict__ x,
                            const float* __restrict__ leaf_w,
                            const float* __restrict__ leaf_b,
                            const float* __restrict__ conv_w,
                            const float* __restrict__ conv_b,
                            const float* __restrict__ bn_gamma,
                            const float* __restrict__ bn_beta,
                            const float* __restrict__ node_w,
                            float* __restrict__ pooled) {
    extern __shared__ float smem[];
    float* buf0 = smem;
    float* buf1 = smem + BUFSZ;
    float* sc   = smem + 2 * BUFSZ;
    float* bt   = sc + 16;

    const int b   = blockIdx.x;
    const int tid = threadIdx.x;

    if (tid < 16) {
        float s = bn_gamma[tid] / sqrtf(1.0f + 1e-5f);
        sc[tid] = s;
        bt[tid] = conv_b[tid] * s + bn_beta[tid];
    }

    {
        const float2 xv  = *(const float2*)(x + b * L + 2 * tid);
        const float2 nw2 = *(const float2*)(node_w + 2 * tid);
        const float4* lwa = (const float4*)(leaf_w + 32 * tid);
        const float4* lba = (const float4*)(leaf_b + 32 * tid);
#pragma unroll 1
        for (int q = 0; q < 4; ++q) {
            float4 w0 = lwa[q],     bb0 = lba[q];
            float4 w1 = lwa[q + 4], bb1 = lba[q + 4];
            float v0[4], v1[4];
            v0[0] = (xv.x * w0.x + bb0.x) * nw2.x;  v1[0] = (xv.y * w1.x + bb1.x) * nw2.y;
            v0[1] = (xv.x * w0.y + bb0.y) * nw2.x;  v1[1] = (xv.y * w1.y + bb1.y) * nw2.y;
            v0[2] = (xv.x * w0.z + bb0.z) * nw2.x;  v1[2] = (xv.y * w1.z + bb1.z) * nw2.y;
            v0[3] = (xv.x * w0.w + bb0.w) * nw2.x;  v1[3] = (xv.y * w1.w + bb1.w) * nw2.y;
#pragma unroll
            for (int j = 0; j < 4; ++j) {
                int c = 4 * q + j;
                buf0[skew((2 * tid) * C + c)]     = v0[j];
                buf0[skew((2 * tid + 1) * C + c)] = v1[j];
                pooled[b * FDIM + c * PCOLS + tid] = fmaxf(v0[j], v1[j]);
            }
        }
        __syncthreads();
    }

    float* bin  = buf0;
    float* bout = buf1;
    int noff = L;
    for (int d = 0; d < NLEV; ++d) {
        const int Lk = 1 << d;
        const int L2 = Lk << 1;
        const int n2 = tid >> d;
        const int tp = tid & (Lk - 1);
        const int t0 = tp << 1;

        int adr[4];
        const bool ok0 = (t0 > 0);
        const bool ok3 = (t0 + 2 < L2);
#pragma unroll
        for (int r = 0; r < 4; ++r) {
            int tt = t0 - 1 + r;
            int ttc = tt < 0 ? 0 : (tt > L2 - 1 ? L2 - 1 : tt);
            int node = 2 * n2 + (ttc >= Lk ? 1 : 0);
            adr[r] = node * (C * Lk) + (ttc & (Lk - 1));
        }

        const float nwv = node_w[noff + n2];
        const int ob = n2 * (C * L2) + t0;
        const int pb = b * FDIM + (d + 1) * POOL + tid;

#pragma unroll 1
        for (int half = 0; half < 2; ++half) {
            float acc0[8], acc1[8];
#pragma unroll
            for (int co = 0; co < 8; ++co) { acc0[co] = 0.f; acc1[co] = 0.f; }

#pragma unroll 1
            for (int cic = 0; cic < 4; ++cic) {
#pragma unroll
                for (int ci4 = 0; ci4 < 4; ++ci4) {
                    const int ci = cic * 4 + ci4;
                    const int o = ci * Lk;
                    float vm1 = ok0 ? bin[skew(adr[0] + o)] : 0.f;
                    float v0  = bin[skew(adr[1] + o)];
                    float v1  = bin[skew(adr[2] + o)];
                    float v2  = ok3 ? bin[skew(adr[3] + o)] : 0.f;
#pragma unroll
                    for (int co = 0; co < 8; ++co) {
                        const float* wp = conv_w + (((half * 8 + co) * C) + ci) * 3;
                        const float wx = wp[0], wy = wp[1], wz = wp[2];
                        acc0[co] = fmaf(wx, vm1, fmaf(wy, v0, fmaf(wz, v1, acc0[co])));
                        acc1[co] = fmaf(wx, v0,  fmaf(wy, v1, fmaf(wz, v2, acc1[co])));
                    }
                }
            }

#pragma unroll
            for (int co = 0; co < 8; ++co) {
                const int c = half * 8 + co;
                float z0 = fmaxf(fmaf(sc[c], acc0[co], bt[c]), 0.f) * nwv;
                float z1 = fmaxf(fmaf(sc[c], acc1[co], bt[c]), 0.f) * nwv;
                bout[skew(ob + c * L2)]     = z0;
                bout[skew(ob + c * L2 + 1)] = z1;
                pooled[pb + c * PCOLS] = fmaxf(z0, z1);
            }
        }

        __syncthreads();
        float* t = bin; bin = bout; bout = t;
        noff += (L >> (d + 1));
    }
}

// ---------------- Kernel 2: fc1 split-K GEMM, LDS double-buffer, 1 barrier/iter --
// grid = 2 * KTv blocks; block (mt,kt) -> partial[kt][b0:b0+128][0:128]
template<int KTv, int KCHv>
__launch_bounds__(512, 2)
__global__ void fc1_partial(const float* __restrict__ pooled,
                            const float* __restrict__ w1,
                            float* __restrict__ partial) {
    extern __shared__ float fsm[];   // [2][ A(128x36) + W(128x36) ]

    const int mt = blockIdx.x & 1;
    const int kt = blockIdx.x >> 1;
    const int b0 = mt * MTILE;
    const int k0 = kt * KCHv;

    const int tid = threadIdx.x;
    const int bg = tid >> 4;       // 0..31 -> rows bg*4 + i
    const int jg = tid & 15;       // 0..15 -> cols jg*8 + j

    const int srow = tid >> 3;     // 0..63
    const int scol = (tid & 7) * 4;

    constexpr int NIT = KCHv / KB;

    float acc[4][8];
#pragma unroll
    for (int i = 0; i < 4; ++i)
#pragma unroll
        for (int j = 0; j < 8; ++j) acc[i][j] = 0.f;

    // prologue: load + stage first K-tile into buf 0
    {
#pragma unroll
        for (int rr = 0; rr < 2; ++rr) {
            int row = rr * 64 + srow;
            float4 av = *(const float4*)(pooled + (long)(b0 + row) * FDIM + k0 + scol);
            float4 wv = *(const float4*)(w1 + (long)row * FDIM + k0 + scol);
            *(float4*)&fsm[row * LDA + (scol ^ (((row >> 2) & 7) << 2))] = av;
            *(float4*)&fsm[ATILE + row * LDA + (scol ^ (((row >> 3) & 7) << 2))] = wv;
        }
    }
    __syncthreads();

    for (int it = 0; it < NIT; ++it) {
        const int p = it & 1;
        const float* Ab = fsm + p * (2 * ATILE);
        const float* Wb = Ab + ATILE;

        // issue next tile's global loads (latency hidden under compute below)
        float4 avn[2], wvn[2];
        const bool more = (it + 1 < NIT);
        if (more) {
            const int kn = k0 + (it + 1) * KB;
#pragma unroll
            for (int rr = 0; rr < 2; ++rr) {
                int row = rr * 64 + srow;
                avn[rr] = *(const float4*)(pooled + (long)(b0 + row) * FDIM + kn + scol);
                wvn[rr] = *(const float4*)(w1 + (long)row * FDIM + kn + scol);
            }
        }

        // compute current tile
#pragma unroll
        for (int kk = 0; kk < KB; kk += 4) {
            float4 av[4], wv[8];
            const int ca = kk ^ ((bg & 7) << 2);     // row=bg*4+i -> (row>>2)&7 == bg&7
            const int cw = kk ^ ((jg & 7) << 2);     // row=jg*8+j -> (row>>3)&7 == jg&7
#pragma unroll
            for (int i = 0; i < 4; ++i) av[i] = *(const float4*)&Ab[(bg * 4 + i) * LDA + ca];
#pragma unroll
            for (int j = 0; j < 8; ++j) wv[j] = *(const float4*)&Wb[(jg * 8 + j) * LDA + cw];
#pragma unroll
            for (int i = 0; i < 4; ++i)
#pragma unroll
                for (int j = 0; j < 8; ++j) {
                    acc[i][j] = fmaf(av[i].x, wv[j].x,
                                fmaf(av[i].y, wv[j].y,
                                fmaf(av[i].z, wv[j].z,
                                fmaf(av[i].w, wv[j].w, acc[i][j]))));
                }
        }

        // write next tile into the other buffer
        if (more) {
            float* An = fsm + (p ^ 1) * (2 * ATILE);
            float* Wn = An + ATILE;
#pragma unroll
            for (int rr = 0; rr < 2; ++rr) {
                int row = rr * 64 + srow;
                *(float4*)&An[row * LDA + (scol ^ (((row >> 2) & 7) << 2))] = avn[rr];
                *(float4*)&Wn[row * LDA + (scol ^ (((row >> 3) & 7) << 2))] = wvn[rr];
            }
        }
        __syncthreads();
    }

#pragma unroll
    for (int i = 0; i < 4; ++i) {
        int brow = b0 + bg * 4 + i;
        float4 o0 = make_float4(acc[i][0], acc[i][1], acc[i][2], acc[i][3]);
        float4 o1 = make_float4(acc[i][4], acc[i][5], acc[i][6], acc[i][7]);
        float* p = partial + (long)kt * (BATCH * H1) + brow * H1 + jg * 8;
        *(float4*)(p)     = o0;
        *(float4*)(p + 4) = o1;
    }
}

// ---------------- Kernel 3: reduce partials + fc1 bias/relu + fc2 + fc3 ----------------
__launch_bounds__(128)
__global__ void fc_tail(const float* __restrict__ partial,
                        const float* __restrict__ fc1_b,
                        const float* __restrict__ w2,
                        const float* __restrict__ b2,
                        const float* __restrict__ w3,
                        const float* __restrict__ b3,
                        float* __restrict__ out, int nkt) {
    __shared__ float h1_s[H1];
    __shared__ float w2_s[H2 * 129];

    const int b = blockIdx.x;
    const int t = threadIdx.x;

    float s = 0.f;
    for (int kt = 0; kt < nkt; ++kt)
        s += partial[(long)kt * (BATCH * H1) + b * H1 + t];
    h1_s[t] = fmaxf(s + fc1_b[t], 0.f);

    for (int i = t; i < H2 * H1; i += 128) {
        int j = i >> 7, k = i & 127;
        w2_s[j * 129 + k] = w2[i];
    }
    __syncthreads();

    if (t < 64) {
        float a2 = 0.f;
#pragma unroll 8
        for (int k = 0; k < H1; ++k) a2 = fmaf(h1_s[k], w2_s[t * 129 + k], a2);
        float h2 = fmaxf(a2 + b2[t], 0.f);
        float r = h2 * w3[t];
#pragma unroll
        for (int off = 32; off > 0; off >>= 1) r += __shfl_down(r, off);
        if (t == 0) out[b] = r + b3[0];
    }
}

extern "C" void kernel_launch(void* const* d_in, const int* in_sizes, int n_in,
                              void* d_out, int out_size, void* d_ws, size_t ws_size,
                              hipStream_t stream) {
    const float* x        = (const float*)d_in[0];
    const float* leaf_w   = (const float*)d_in[1];
    const float* leaf_b   = (const float*)d_in[2];
    const float* conv_w   = (const float*)d_in[3];
    const float* conv_b   = (const float*)d_in[4];
    const float* bn_gamma = (const float*)d_in[5];
    const float* bn_beta  = (const float*)d_in[6];
    const float* node_w   = (const float*)d_in[7];
    const float* fc1_w    = (const float*)d_in[8];
    const float* fc1_b    = (const float*)d_in[9];
    const float* fc2_w    = (const float*)d_in[10];
    const float* fc2_b    = (const float*)d_in[11];
    const float* fc3_w    = (const float*)d_in[12];
    const float* fc3_b    = (const float*)d_in[13];

    float* pooled  = (float*)d_ws;                        // 92.3 MB
    float* partial = pooled + (long)BATCH * FDIM;

    (void)hipFuncSetAttribute((const void*)tree_kernel,
                        hipFuncAttributeMaxDynamicSharedMemorySize, TREE_LDS_BYTES);

    tree_kernel<<<BATCH, 512, TREE_LDS_BYTES, stream>>>(
        x, leaf_w, leaf_b, conv_w, conv_b, bn_gamma, bn_beta, node_w, pooled);

    // pick split-K width by workspace room: KT=256 -> 2 blocks/CU, partial 33.5 MB
    const size_t need256 = ((size_t)BATCH * FDIM + (size_t)256 * BATCH * H1) * 4;
    if (ws_size >= need256) {
        (void)hipFuncSetAttribute((const void*)fc1_partial<256, 352>,
                        hipFuncAttributeMaxDynamicSharedMemorySize, FC1_LDS_BYTES);
        fc1_partial<256, 352><<<512, 512, FC1_LDS_BYTES, stream>>>(pooled, fc1_w, partial);
        fc_tail<<<BATCH, 128, 0, stream>>>(partial, fc1_b, fc2_w, fc2_b, fc3_w, fc3_b,
                                           (float*)d_out, 256);
    } else {
        (void)hipFuncSetAttribute((const void*)fc1_partial<128, 704>,
                        hipFuncAttributeMaxDynamicSharedMemorySize, FC1_LDS_BYTES);
        fc1_partial<128, 704><<<256, 512, FC1_LDS_BYTES, stream>>>(pooled, fc1_w, partial);
        fc_tail<<<BATCH, 128, 0, stream>>>(partial, fc1_b, fc2_w, fc2_b, fc3_w, fc3_b,
                                           (float*)d_out, 128);
    }
}

// Round 15
// 197.952 us; speedup vs baseline: 5.4099x; 5.4099x over previous
//
#include <hip/hip_runtime.h>

#define BATCH 256
#define L 1024
#define C 16
#define NLEV 10
#define POOL 512
#define PCOLS 5632
#define FDIM 90112        // C*PCOLS
#define H1 128
#define H2 64

#define KS 64             // split-K factor for mfma GEMM
#define KCHUNK (FDIM / KS)   // 1408

#define BUFSZ 16896
#define TREE_LDS_BYTES ((2*BUFSZ + 32) * 4)

typedef float f32x4 __attribute__((ext_vector_type(4)));
typedef short bf16x8 __attribute__((ext_vector_type(8)));

__device__ __forceinline__ int skew(int i) { return i + (i >> 5); }

__device__ __forceinline__ unsigned short f2b(float f) {
    union { float f; unsigned int u; } v; v.f = f;
    unsigned int r = (v.u + 0x7FFFu + ((v.u >> 16) & 1u)) >> 16;   // RNE
    return (unsigned short)r;
}

// ---------------- Kernel 1: tree (R13-proven) -> pooled in BF16 ----------------
__launch_bounds__(512, 2)
__global__ void tree_kernel(const float* __restrict__ x,
                            const float* __restrict__ leaf_w,
                            const float* __restrict__ leaf_b,
                            const float* __restrict__ conv_w,
                            const float* __restrict__ conv_b,
                            const float* __restrict__ bn_gamma,
                            const float* __restrict__ bn_beta,
                            const float* __restrict__ node_w,
                            unsigned short* __restrict__ pooledb) {
    extern __shared__ float smem[];
    float* buf0 = smem;
    float* buf1 = smem + BUFSZ;
    float* sc   = smem + 2 * BUFSZ;
    float* bt   = sc + 16;

    const int b   = blockIdx.x;
    const int tid = threadIdx.x;

    if (tid < 16) {
        float s = bn_gamma[tid] / sqrtf(1.0f + 1e-5f);
        sc[tid] = s;
        bt[tid] = conv_b[tid] * s + bn_beta[tid];
    }

    {
        const float2 xv  = *(const float2*)(x + b * L + 2 * tid);
        const float2 nw2 = *(const float2*)(node_w + 2 * tid);
        const float4* lwa = (const float4*)(leaf_w + 32 * tid);
        const float4* lba = (const float4*)(leaf_b + 32 * tid);
#pragma unroll 1
        for (int q = 0; q < 4; ++q) {
            float4 w0 = lwa[q],     bb0 = lba[q];
            float4 w1 = lwa[q + 4], bb1 = lba[q + 4];
            float v0[4], v1[4];
            v0[0] = (xv.x * w0.x + bb0.x) * nw2.x;  v1[0] = (xv.y * w1.x + bb1.x) * nw2.y;
            v0[1] = (xv.x * w0.y + bb0.y) * nw2.x;  v1[1] = (xv.y * w1.y + bb1.y) * nw2.y;
            v0[2] = (xv.x * w0.z + bb0.z) * nw2.x;  v1[2] = (xv.y * w1.z + bb1.z) * nw2.y;
            v0[3] = (xv.x * w0.w + bb0.w) * nw2.x;  v1[3] = (xv.y * w1.w + bb1.w) * nw2.y;
#pragma unroll
            for (int j = 0; j < 4; ++j) {
                int c = 4 * q + j;
                buf0[skew((2 * tid) * C + c)]     = v0[j];
                buf0[skew((2 * tid + 1) * C + c)] = v1[j];
                pooledb[b * FDIM + c * PCOLS + tid] = f2b(fmaxf(v0[j], v1[j]));
            }
        }
        __syncthreads();
    }

    float* bin  = buf0;
    float* bout = buf1;
    int noff = L;
    for (int d = 0; d < NLEV; ++d) {
        const int Lk = 1 << d;
        const int L2 = Lk << 1;
        const int n2 = tid >> d;
        const int tp = tid & (Lk - 1);
        const int t0 = tp << 1;

        int adr[4];
        const bool ok0 = (t0 > 0);
        const bool ok3 = (t0 + 2 < L2);
#pragma unroll
        for (int r = 0; r < 4; ++r) {
            int tt = t0 - 1 + r;
            int ttc = tt < 0 ? 0 : (tt > L2 - 1 ? L2 - 1 : tt);
            int node = 2 * n2 + (ttc >= Lk ? 1 : 0);
            adr[r] = node * (C * Lk) + (ttc & (Lk - 1));
        }

        const float nwv = node_w[noff + n2];
        const int ob = n2 * (C * L2) + t0;
        const int pb = b * FDIM + (d + 1) * POOL + tid;

#pragma unroll 1
        for (int half = 0; half < 2; ++half) {
            float acc0[8], acc1[8];
#pragma unroll
            for (int co = 0; co < 8; ++co) { acc0[co] = 0.f; acc1[co] = 0.f; }

#pragma unroll 1
            for (int cic = 0; cic < 4; ++cic) {
#pragma unroll
                for (int ci4 = 0; ci4 < 4; ++ci4) {
                    const int ci = cic * 4 + ci4;
                    const int o = ci * Lk;
                    float vm1 = ok0 ? bin[skew(adr[0] + o)] : 0.f;
                    float v0  = bin[skew(adr[1] + o)];
                    float v1  = bin[skew(adr[2] + o)];
                    float v2  = ok3 ? bin[skew(adr[3] + o)] : 0.f;
#pragma unroll
                    for (int co = 0; co < 8; ++co) {
                        const float* wp = conv_w + (((half * 8 + co) * C) + ci) * 3;
                        const float wx = wp[0], wy = wp[1], wz = wp[2];
                        acc0[co] = fmaf(wx, vm1, fmaf(wy, v0, fmaf(wz, v1, acc0[co])));
                        acc1[co] = fmaf(wx, v0,  fmaf(wy, v1, fmaf(wz, v2, acc1[co])));
                    }
                }
            }

#pragma unroll
            for (int co = 0; co < 8; ++co) {
                const int c = half * 8 + co;
                float z0 = fmaxf(fmaf(sc[c], acc0[co], bt[c]), 0.f) * nwv;
                float z1 = fmaxf(fmaf(sc[c], acc1[co], bt[c]), 0.f) * nwv;
                bout[skew(ob + c * L2)]     = z0;
                bout[skew(ob + c * L2 + 1)] = z1;
                pooledb[pb + c * PCOLS] = f2b(fmaxf(z0, z1));
            }
        }

        __syncthreads();
        float* t = bin; bin = bout; bout = t;
        noff += (L >> (d + 1));
    }
}

// ---------------- Kernel 1b: fc1_w f32 -> bf16 ----------------
__launch_bounds__(256)
__global__ void w1_convert(const float* __restrict__ w1,
                           unsigned short* __restrict__ w1b) {
    const int n4 = (H1 * FDIM) >> 2;     // float4 count
    for (int i = blockIdx.x * blockDim.x + threadIdx.x; i < n4;
         i += gridDim.x * blockDim.x) {
        float4 v = *(const float4*)(w1 + 4 * i);
        ushort4 o;
        o.x = f2b(v.x); o.y = f2b(v.y); o.z = f2b(v.z); o.w = f2b(v.w);
        *(ushort4*)(w1b + 4 * i) = o;
    }
}

// ---------------- Kernel 2: fc1 via MFMA bf16, split-K, no LDS ----------------
// grid 512: bid = [bm(2b)|bn(1b)|ks(6b)]; block 256 thr = 4 waves (m-stacked).
// Wave: 16 rows x 64 cols (4 n-tiles), K-chunk 1408.
__launch_bounds__(256, 2)
__global__ void fc1_mfma(const unsigned short* __restrict__ pooledb,
                         const unsigned short* __restrict__ w1b,
                         float* __restrict__ partial) {
    const int bid = blockIdx.x;
    const int ks  = bid & (KS - 1);
    const int g   = bid >> 6;            // 0..7
    const int bm  = g >> 1;              // 0..3
    const int bn  = g & 1;               // 0..1

    const int tid  = threadIdx.x;
    const int wv   = tid >> 6;           // wave 0..3
    const int lane = tid & 63;

    const int m0 = bm * 64 + wv * 16;    // wave's row base
    const int n0 = bn * 64;              // wave's col base
    const int kb = ks * KCHUNK;

    const int lrow = lane & 15;
    const int lk   = (lane >> 4) * 8;

    const unsigned short* ap = pooledb + (long)(m0 + lrow) * FDIM + kb + lk;
    const unsigned short* bp0 = w1b + (long)(n0 + lrow) * FDIM + kb + lk;

    f32x4 acc0 = {0.f, 0.f, 0.f, 0.f};
    f32x4 acc1 = {0.f, 0.f, 0.f, 0.f};
    f32x4 acc2 = {0.f, 0.f, 0.f, 0.f};
    f32x4 acc3 = {0.f, 0.f, 0.f, 0.f};

#pragma unroll 2
    for (int kk = 0; kk < KCHUNK; kk += 32) {
        bf16x8 a  = *(const bf16x8*)(ap + kk);
        bf16x8 b0 = *(const bf16x8*)(bp0 + kk);
        bf16x8 b1 = *(const bf16x8*)(bp0 + 16 * FDIM + kk);
        bf16x8 b2 = *(const bf16x8*)(bp0 + 32 * FDIM + kk);
        bf16x8 b3 = *(const bf16x8*)(bp0 + 48 * FDIM + kk);
        acc0 = __builtin_amdgcn_mfma_f32_16x16x32_bf16(a, b0, acc0, 0, 0, 0);
        acc1 = __builtin_amdgcn_mfma_f32_16x16x32_bf16(a, b1, acc1, 0, 0, 0);
        acc2 = __builtin_amdgcn_mfma_f32_16x16x32_bf16(a, b2, acc2, 0, 0, 0);
        acc3 = __builtin_amdgcn_mfma_f32_16x16x32_bf16(a, b3, acc3, 0, 0, 0);
    }

    // C/D layout: col = lane&15, row = (lane>>4)*4 + reg   [m89-verified]
    const int crow = m0 + (lane >> 4) * 4;
    const int ccol = n0 + (lane & 15);
    float* pp = partial + (long)ks * (BATCH * H1) + (long)crow * H1 + ccol;
#pragma unroll
    for (int r = 0; r < 4; ++r) {
        pp[(long)r * H1]            = acc0[r];
        pp[(long)r * H1 + 16]       = acc1[r];
        pp[(long)r * H1 + 32]       = acc2[r];
        pp[(long)r * H1 + 48]       = acc3[r];
    }
}

// ---------------- Kernel 3: reduce partials + fc1 bias/relu + fc2 + fc3 ----------
__launch_bounds__(128)
__global__ void fc_tail(const float* __restrict__ partial,
                        const float* __restrict__ fc1_b,
                        const float* __restrict__ w2,
                        const float* __restrict__ b2,
                        const float* __restrict__ w3,
                        const float* __restrict__ b3,
                        float* __restrict__ out, int nkt) {
    __shared__ float h1_s[H1];
    __shared__ float w2_s[H2 * 129];

    const int b = blockIdx.x;
    const int t = threadIdx.x;

    float s = 0.f;
    for (int kt = 0; kt < nkt; ++kt)
        s += partial[(long)kt * (BATCH * H1) + b * H1 + t];
    h1_s[t] = fmaxf(s + fc1_b[t], 0.f);

    for (int i = t; i < H2 * H1; i += 128) {
        int j = i >> 7, k = i & 127;
        w2_s[j * 129 + k] = w2[i];
    }
    __syncthreads();

    if (t < 64) {
        float a2 = 0.f;
#pragma unroll 8
        for (int k = 0; k < H1; ++k) a2 = fmaf(h1_s[k], w2_s[t * 129 + k], a2);
        float h2 = fmaxf(a2 + b2[t], 0.f);
        float r = h2 * w3[t];
#pragma unroll
        for (int off = 32; off > 0; off >>= 1) r += __shfl_down(r, off);
        if (t == 0) out[b] = r + b3[0];
    }
}

extern "C" void kernel_launch(void* const* d_in, const int* in_sizes, int n_in,
                              void* d_out, int out_size, void* d_ws, size_t ws_size,
                              hipStream_t stream) {
    const float* x        = (const float*)d_in[0];
    const float* leaf_w   = (const float*)d_in[1];
    const float* leaf_b   = (const float*)d_in[2];
    const float* conv_w   = (const float*)d_in[3];
    const float* conv_b   = (const float*)d_in[4];
    const float* bn_gamma = (const float*)d_in[5];
    const float* bn_beta  = (const float*)d_in[6];
    const float* node_w   = (const float*)d_in[7];
    const float* fc1_w    = (const float*)d_in[8];
    const float* fc1_b    = (const float*)d_in[9];
    const float* fc2_w    = (const float*)d_in[10];
    const float* fc2_b    = (const float*)d_in[11];
    const float* fc3_w    = (const float*)d_in[12];
    const float* fc3_b    = (const float*)d_in[13];

    // ws layout: pooled bf16 (46.1 MB) | w1 bf16 (23.1 MB) | partial f32 (8.4 MB)
    unsigned short* pooledb = (unsigned short*)d_ws;
    unsigned short* w1b     = pooledb + (long)BATCH * FDIM;
    float*          partial = (float*)(w1b + (long)H1 * FDIM);

    (void)hipFuncSetAttribute((const void*)tree_kernel,
                        hipFuncAttributeMaxDynamicSharedMemorySize, TREE_LDS_BYTES);

    w1_convert<<<1024, 256, 0, stream>>>(fc1_w, w1b);

    tree_kernel<<<BATCH, 512, TREE_LDS_BYTES, stream>>>(
        x, leaf_w, leaf_b, conv_w, conv_b, bn_gamma, bn_beta, node_w, pooledb);

    fc1_mfma<<<512, 256, 0, stream>>>(pooledb, w1b, partial);

    fc_tail<<<BATCH, 128, 0, stream>>>(partial, fc1_b, fc2_w, fc2_b, fc3_w, fc3_b,
                                       (float*)d_out, KS);
}